// Round 6
// baseline (160.902 us; speedup 1.0000x reference)
//
#include <hip/hip_runtime.h>

// Actor MLP, B=262144 rows, fp32. 4 threads per row (quarters q=tid>>7,
// wave-uniform). R5 post-mortem: 64-float z-half still spilled (VGPR_Count=48,
// WRITE_SIZE 108MB vs 31MB real output). Fix: 32 z-floats/thread held as 8
// aligned f4v tuples; all weight reads stay readfirstlane-uniform -> s_load.
// Phase3 reduction: two-pass deterministic LDS add, stride 31 conflict-free.

typedef float f16v __attribute__((ext_vector_type(16)));
typedef float f4v  __attribute__((ext_vector_type(4)));

constexpr int NG = 14, GI = 9, FH = 128, AD = 15;
constexpr int RPB  = 128;   // rows per 512-thread block
constexpr int SSTR = 57;    // s region stride (odd -> conflict-free)
constexpr int PSTR = 31;    // partials stride (odd -> conflict-free)

__device__ __forceinline__ f4v load4u(const float* p) {
    f4v v; __builtin_memcpy(&v, p, 16); return v;   // 4B-aligned dwordx4
}

__global__ void w4t_kernel(const float* __restrict__ W4, float* __restrict__ W4T) {
    int t = blockIdx.x * 256 + threadIdx.x;
    if (t < FH * 2 * AD) {
        int j = t / (2 * AD), k = t % (2 * AD);   // W4[j][k]
        W4T[(size_t)k * FH + j] = W4[t];
    }
}

__global__ __launch_bounds__(512, 6) void actor_fused(
    const float* __restrict__ x,     // [B,126]
    const float* __restrict__ sale,  // [B,1]
    const float* __restrict__ W1,    // [9,16]
    const float* __restrict__ b1,    // [16]
    const float* __restrict__ W2,    // [16,4]
    const float* __restrict__ b2,    // [4]
    const float* __restrict__ W3,    // [57,128]
    const float* __restrict__ b3,    // [128]
    const float* __restrict__ W4T,   // [30,128] (transposed, in ws)
    const float* __restrict__ b4,    // [30]
    float* __restrict__ om, float* __restrict__ os, int B)
{
    // union: phase1/2 = s values [RPB][57]; phase3 = partials [2][RPB][31]
    __shared__ float smem[2 * RPB * PSTR];   // 7936 floats = 31.7 KB

    const int tid = threadIdx.x;
    const int q   = __builtin_amdgcn_readfirstlane(tid >> 7);  // quarter 0..3
    const int r   = tid & (RPB - 1);
    const int row = blockIdx.x * RPB + r;

    // wave-uniform work split: groups (4,4,3,3), z columns q*32..q*32+31
    const int gbase = __builtin_amdgcn_readfirstlane(4 * q - (q == 3 ? 1 : 0));
    const int gcnt  = __builtin_amdgcn_readfirstlane(q >= 2 ? 3 : 4);
    const int zoff  = __builtin_amdgcn_readfirstlane(q * 32);

    const f16v* w1v = (const f16v*)W1;
    const f4v*  w2v = (const f4v*)W2;
    const f16v  b1v = *(const f16v*)b1;
    const f4v   b2v = *(const f4v*)b2;
    float* srow = smem + r * SSTR;

    // ---- phase 1: shared block for groups [gbase, gbase+gcnt) ----
    const float* xr = x + (size_t)row * (NG * GI);
    #pragma unroll 1
    for (int g = 0; g < gcnt; ++g) {
        const int gg = gbase + g;
        const float* xg = xr + gg * GI;
        f4v ca = load4u(xg), cb = load4u(xg + 4);
        float cs = xg[8];

        f16v h = b1v;
        h += ca[0] * w1v[0]; h += ca[1] * w1v[1]; h += ca[2] * w1v[2];
        h += ca[3] * w1v[3]; h += cb[0] * w1v[4]; h += cb[1] * w1v[5];
        h += cb[2] * w1v[6]; h += cb[3] * w1v[7]; h += cs    * w1v[8];
        h = __builtin_elementwise_max(h, (f16v)0.f);

        f4v s = b2v;
        s += h[0]  * w2v[0];  s += h[1]  * w2v[1];  s += h[2]  * w2v[2];  s += h[3]  * w2v[3];
        s += h[4]  * w2v[4];  s += h[5]  * w2v[5];  s += h[6]  * w2v[6];  s += h[7]  * w2v[7];
        s += h[8]  * w2v[8];  s += h[9]  * w2v[9];  s += h[10] * w2v[10]; s += h[11] * w2v[11];
        s += h[12] * w2v[12]; s += h[13] * w2v[13]; s += h[14] * w2v[14]; s += h[15] * w2v[15];
        s = __builtin_elementwise_max(s, (f4v)0.f);

        int c = gg * 4;
        srow[c + 0] = s[0]; srow[c + 1] = s[1];
        srow[c + 2] = s[2]; srow[c + 3] = s[3];
    }
    if (q == 3) srow[56] = sale[row];
    __syncthreads();

    // ---- phase 2: z-quarter[32] = relu(b3q + sum_c s[c]*W3[c][zoff..+32)) ----
    const float* b3h = b3 + zoff;   // uniform -> s_load
    const float* w3q = W3 + zoff;   // uniform -> s_load
    f4v z0 = load4u(b3h +  0), z1 = load4u(b3h +  4);
    f4v z2 = load4u(b3h +  8), z3 = load4u(b3h + 12);
    f4v z4 = load4u(b3h + 16), z5 = load4u(b3h + 20);
    f4v z6 = load4u(b3h + 24), z7 = load4u(b3h + 28);
    #pragma unroll 1
    for (int c = 0; c < 57; ++c) {
        float sv = srow[c];
        const f4v* wv = (const f4v*)(w3q + (size_t)c * FH);
        z0 += sv * wv[0]; z1 += sv * wv[1]; z2 += sv * wv[2]; z3 += sv * wv[3];
        z4 += sv * wv[4]; z5 += sv * wv[5]; z6 += sv * wv[6]; z7 += sv * wv[7];
    }
    z0 = __builtin_elementwise_max(z0, (f4v)0.f);
    z1 = __builtin_elementwise_max(z1, (f4v)0.f);
    z2 = __builtin_elementwise_max(z2, (f4v)0.f);
    z3 = __builtin_elementwise_max(z3, (f4v)0.f);
    z4 = __builtin_elementwise_max(z4, (f4v)0.f);
    z5 = __builtin_elementwise_max(z5, (f4v)0.f);
    z6 = __builtin_elementwise_max(z6, (f4v)0.f);
    z7 = __builtin_elementwise_max(z7, (f4v)0.f);
    __syncthreads();   // all s reads done; smem reused for partials

    // ---- phase 3: partial dots over own 32 z; two-pass deterministic add ----
    float* prow = smem + ((size_t)(q & 1) * RPB + r) * PSTR;
    if (q >= 2) {      // pass 1: quarters 2,3 write their partials
        #pragma unroll 1
        for (int k = 0; k < 2 * AD; ++k) {
            const f4v* wv = (const f4v*)(W4T + (size_t)k * FH + zoff);  // uniform
            f4v a = z0 * wv[0];
            a += z1 * wv[1]; a += z2 * wv[2]; a += z3 * wv[3];
            a += z4 * wv[4]; a += z5 * wv[5]; a += z6 * wv[6]; a += z7 * wv[7];
            prow[k] = (a[0] + a[1]) + (a[2] + a[3]);
        }
    }
    __syncthreads();
    if (q < 2) {       // pass 2: quarters 0,1 accumulate into same slots
        #pragma unroll 1
        for (int k = 0; k < 2 * AD; ++k) {
            const f4v* wv = (const f4v*)(W4T + (size_t)k * FH + zoff);  // uniform
            f4v a = z0 * wv[0];
            a += z1 * wv[1]; a += z2 * wv[2]; a += z3 * wv[3];
            a += z4 * wv[4]; a += z5 * wv[5]; a += z6 * wv[6]; a += z7 * wv[7];
            prow[k] += (a[0] + a[1]) + (a[2] + a[3]);
        }
    }
    __syncthreads();

    // ---- finalize: quarter q handles outputs [8q, 8q+8) (q3: 6) ----
    const int koff = q * 8;
    const int kcnt = (q == 3) ? 6 : 8;
    size_t ob = (size_t)row * AD;
    #pragma unroll 1
    for (int i = 0; i < kcnt; ++i) {
        int k = koff + i;
        float v = smem[r * PSTR + k] + smem[(RPB + r) * PSTR + k] + b4[k];
        if (k < AD) {
            float tc = fminf(fmaxf(v, -20.f), 20.f);
            float e = __expf(2.f * tc);
            om[ob + k] = (e - 1.f) / (e + 1.f);
        } else {
            os[ob + (k - AD)] = __expf(v);
        }
    }
}

extern "C" void kernel_launch(void* const* d_in, const int* in_sizes, int n_in,
                              void* d_out, int out_size, void* d_ws, size_t ws_size,
                              hipStream_t stream) {
    const float* x    = (const float*)d_in[0];
    const float* sale = (const float*)d_in[1];
    const float* W1   = (const float*)d_in[2];
    const float* b1   = (const float*)d_in[3];
    const float* W2   = (const float*)d_in[4];
    const float* b2   = (const float*)d_in[5];
    const float* W3   = (const float*)d_in[6];
    const float* b3   = (const float*)d_in[7];
    const float* W4   = (const float*)d_in[8];
    const float* b4   = (const float*)d_in[9];

    int B = in_sizes[1];                       // sale_predictions is [B,1]
    float* om = (float*)d_out;                 // action_mean flat [B*15]
    float* os = om + (size_t)B * AD;           // action_std  flat [B*15]
    float* W4T = (float*)d_ws;                 // [30,128]

    w4t_kernel<<<(FH * 2 * AD + 255) / 256, 256, 0, stream>>>(W4, W4T);
    int grid = B / RPB;                        // 2048 blocks
    actor_fused<<<grid, 512, 0, stream>>>(x, sale, W1, b1, W2, b2, W3, b3,
                                          W4T, b4, om, os, B);
}